// Round 7
// baseline (165.693 us; speedup 1.0000x reference)
//
#include <hip/hip_runtime.h>
#include <hip/hip_bf16.h>

#define VOCAB 100000
#define EMBED 64
#define SENT  20
#define MEM   50
#define BATCH 32
#define HOPS  3

// 4 gather sets: t=0 -> A (m for hop0); t=1..3 -> C[t-1] (c for hop t-1, m for hop t).
// Exploits m_h == c_{h-1} (same table, same words, same encoding).
#define NSET  4
#define NSLOT (NSET * BATCH * MEM)   // 6400

__device__ __forceinline__ float bfr(unsigned short x) {
    union { unsigned int u; float f; } cv;
    cv.u = ((unsigned int)x) << 16;
    return cv.f;
}

// Runtime dtype probe: enc row 19 (last) is exactly 1.0 everywhere.
// bf16 storage: dword 639 packs elements 1278,1279 = (1.0bf,1.0bf) = 0x3F803F80.
__device__ __forceinline__ bool is_bf16(const void* enc) {
    return ((const unsigned int*)enc)[639] == 0x3F803F80u;
}

__device__ __forceinline__ float loadT(const void* p, size_t idx, bool bf) {
    return bf ? bfr(((const unsigned short*)p)[idx]) : ((const float*)p)[idx];
}

__device__ __forceinline__ float wave_sum(float d) {
#pragma unroll
    for (int off = 32; off > 0; off >>= 1) d += __shfl_xor(d, off, 64);
    return d;
}

// Wave gw < 6400 computes one (t, bm) position-encoded sentence vector:
//   mc_ws[gw][e] = sum_s T_t[w_s][e] * enc[s][e]
// Waves 6400..6431 compute u0 for batch gw-6400.   (R6-proven)
__global__ __launch_bounds__(256) void k_gather(
    const int* __restrict__ stories,   // [32,50,20]
    const int* __restrict__ queries,   // [32,20]
    const void* __restrict__ A,        // [V,64]
    const void* __restrict__ C,        // [3,V,64]
    const void* __restrict__ enc,      // [20,64]
    float* __restrict__ mc_ws,         // [6400,64]
    float* __restrict__ u0g)           // [32,64]
{
    const bool bf = is_bf16(enc);
    const int tid = threadIdx.x;
    const int e   = tid & 63;
    const int gw  = blockIdx.x * 4 + (tid >> 6);
    const size_t VE = (size_t)VOCAB * EMBED;

    float encr[SENT];
#pragma unroll
    for (int s = 0; s < SENT; ++s) encr[s] = loadT(enc, s * EMBED + e, bf);

    if (gw < NSLOT) {
        const int t  = gw / (BATCH * MEM);
        const int bm = gw % (BATCH * MEM);
        const void* T   = (t == 0) ? A : C;
        const size_t to = (t == 0) ? 0 : (size_t)(t - 1) * VE;

        int wst = (e < SENT) ? stories[bm * SENT + e] : 0;
        float acc = 0.f;
#pragma unroll
        for (int s = 0; s < SENT; ++s) {
            int w = __shfl(wst, s, 64);
            acc += loadT(T, to + (size_t)w * EMBED + e, bf) * encr[s];
        }
        mc_ws[gw * EMBED + e] = acc;
    } else if (gw < NSLOT + BATCH) {
        const int b = gw - NSLOT;
        int wq = (e < SENT) ? queries[b * SENT + e] : 0;
        float u = 0.f;
#pragma unroll
        for (int s = 0; s < SENT; ++s) {
            int w = __shfl(wq, s, 64);
            u += loadT(A, (size_t)w * EMBED + e, bf) * encr[s];
        }
        u0g[b * EMBED + e] = u;
    }
}

// One block (256 thr = 4 waves) per batch; LDS recurrence.  (R6-proven)
__global__ __launch_bounds__(256) void k_recur2(
    const float* __restrict__ mc_ws,   // [4,1600,64] = [t][b*50+mm][e]
    const float* __restrict__ u0g,
    float* __restrict__ u3g)
{
    const int b    = blockIdx.x;
    const int tid  = threadIdx.x;
    const int lane = tid & 63;
    const int widx = tid >> 6;

    __shared__ float mc[NSET][MEM][65];   // 52 KB
    __shared__ float uls[EMBED];
    __shared__ float ols[4][EMBED];

    for (int idx = tid; idx < NSET * MEM * 16; idx += 256) {
        int t  = idx / (MEM * 16);
        int r  = idx % (MEM * 16);
        int mm = r >> 4;
        int e4 = r & 15;
        const float4 v = *(const float4*)(mc_ws +
            (((size_t)t * BATCH * MEM) + (size_t)b * MEM + mm) * EMBED + e4 * 4);
        mc[t][mm][e4 * 4 + 0] = v.x;
        mc[t][mm][e4 * 4 + 1] = v.y;
        mc[t][mm][e4 * 4 + 2] = v.z;
        mc[t][mm][e4 * 4 + 3] = v.w;
    }
    if (tid < EMBED) uls[tid] = u0g[b * EMBED + tid];
    __syncthreads();

    for (int hop = 0; hop < HOPS; ++hop) {
        float d = 0.f;
        if (lane < MEM) {
#pragma unroll
            for (int e = 0; e < EMBED; ++e)
                d += mc[hop][lane][e] * uls[e];
        }
        float x = (lane < MEM) ? d : -3.4e38f;
        float mx = x;
#pragma unroll
        for (int off = 32; off > 0; off >>= 1) mx = fmaxf(mx, __shfl_xor(mx, off, 64));
        float ex = (lane < MEM) ? __expf(x - mx) : 0.f;
        float sm = wave_sum(ex);
        float p = ex / sm;

        float o = 0.f;
#pragma unroll
        for (int k = 0; k < 13; ++k) {
            int mm = widx * 13 + k;
            if (mm < MEM)
                o += __shfl(p, mm, 64) * mc[hop + 1][mm][lane];
        }
        ols[widx][lane] = o;
        __syncthreads();
        if (tid < EMBED)
            uls[tid] += ols[0][tid] + ols[1][tid] + ols[2][tid] + ols[3][tid];
        __syncthreads();
    }

    if (tid < EMBED) u3g[b * EMBED + tid] = uls[tid];
}

// out[b*V+v] = sum_e u3[b][e] * C[2][v][e]
// Rewritten: 2 threads per v (16 batches each), K chunked by 8 so per-thread
// state is res[16]+rf[8] (~40 VGPR, no scratch spill). su reads are
// uniform-address LDS float4 broadcasts (conflict-free).
__global__ __launch_bounds__(256) void k_out(const float* __restrict__ u,
                                             const void* __restrict__ Cbase,
                                             const void* __restrict__ enc,
                                             void* __restrict__ out)
{
    const bool bf = is_bf16(enc);
    const size_t c2_off = (size_t)2 * VOCAB * EMBED;

    __shared__ __align__(16) float su[BATCH * EMBED];
    for (int i = threadIdx.x; i < BATCH * EMBED; i += 256) su[i] = u[i];
    __syncthreads();

    const int v  = blockIdx.x * 128 + (threadIdx.x & 127);
    const int bh = threadIdx.x >> 7;            // batch half: 0 -> 0..15, 1 -> 16..31
    if (v >= VOCAB) return;

    float res[16];
#pragma unroll
    for (int i = 0; i < 16; ++i) res[i] = 0.f;

    // su base for this half; per chunk kc the two float4's per batch are
    // sp[b*16 + kc*2] and sp[b*16 + kc*2 + 1]
    const float4* sp = (const float4*)(su + bh * 16 * EMBED);

    if (bf) {
        const uint4* rp = (const uint4*)((const unsigned short*)Cbase + c2_off + (size_t)v * EMBED);
#pragma unroll
        for (int kc = 0; kc < 8; ++kc) {
            uint4 r = rp[kc];
            float rf[8];
            rf[0] = bfr((unsigned short)(r.x & 0xffff));
            rf[1] = bfr((unsigned short)(r.x >> 16));
            rf[2] = bfr((unsigned short)(r.y & 0xffff));
            rf[3] = bfr((unsigned short)(r.y >> 16));
            rf[4] = bfr((unsigned short)(r.z & 0xffff));
            rf[5] = bfr((unsigned short)(r.z >> 16));
            rf[6] = bfr((unsigned short)(r.w & 0xffff));
            rf[7] = bfr((unsigned short)(r.w >> 16));
#pragma unroll
            for (int b = 0; b < 16; ++b) {
                float4 a0 = sp[b * 16 + kc * 2];
                float4 a1 = sp[b * 16 + kc * 2 + 1];
                res[b] += rf[0]*a0.x + rf[1]*a0.y + rf[2]*a0.z + rf[3]*a0.w
                        + rf[4]*a1.x + rf[5]*a1.y + rf[6]*a1.z + rf[7]*a1.w;
            }
        }
    } else {
        const float4* rp = (const float4*)((const float*)Cbase + c2_off + (size_t)v * EMBED);
#pragma unroll
        for (int kc = 0; kc < 8; ++kc) {
            float4 r0 = rp[kc * 2];
            float4 r1 = rp[kc * 2 + 1];
            float rf[8] = { r0.x, r0.y, r0.z, r0.w, r1.x, r1.y, r1.z, r1.w };
#pragma unroll
            for (int b = 0; b < 16; ++b) {
                float4 a0 = sp[b * 16 + kc * 2];
                float4 a1 = sp[b * 16 + kc * 2 + 1];
                res[b] += rf[0]*a0.x + rf[1]*a0.y + rf[2]*a0.z + rf[3]*a0.w
                        + rf[4]*a1.x + rf[5]*a1.y + rf[6]*a1.z + rf[7]*a1.w;
            }
        }
    }

    if (bf) {
        unsigned short* ob = (unsigned short*)out;
#pragma unroll
        for (int b = 0; b < 16; ++b) {
            __hip_bfloat16 h = __float2bfloat16(res[b]);
            ob[(size_t)(bh * 16 + b) * VOCAB + v] = *(unsigned short*)&h;
        }
    } else {
        float* of = (float*)out;
#pragma unroll
        for (int b = 0; b < 16; ++b)
            of[(size_t)(bh * 16 + b) * VOCAB + v] = res[b];
    }
}

extern "C" void kernel_launch(void* const* d_in, const int* in_sizes, int n_in,
                              void* d_out, int out_size, void* d_ws, size_t ws_size,
                              hipStream_t stream)
{
    const int*  stories = (const int*)d_in[0];
    const int*  queries = (const int*)d_in[1];
    const void* A       = d_in[2];
    const void* C       = d_in[3];
    const void* enc     = d_in[4];

    float* mc_ws = (float*)d_ws;                 // [6400,64]
    float* u0g   = mc_ws + NSLOT * EMBED;        // [32,64]
    float* u3g   = u0g + BATCH * EMBED;          // [32,64]

    const int nwaves  = NSLOT + BATCH;           // 6432
    const int nblocks = (nwaves + 3) / 4;        // 1608

    k_gather<<<nblocks, 256, 0, stream>>>(stories, queries, A, C, enc, mc_ws, u0g);
    k_recur2<<<BATCH, 256, 0, stream>>>(mc_ws, u0g, u3g);
    k_out<<<(VOCAB + 127) / 128, 256, 0, stream>>>(u3g, C, enc, d_out);
}